// Round 3
// baseline (272.446 us; speedup 1.0000x reference)
//
#include <hip/hip_runtime.h>

// WaveNet-ish: 10 stacked causal dilated conv1d (1ch, k=2, dil=2^i), then 1x1 -> 256ch.
// B=16, T=16384, receptive shrink 1023, final length 15361, classes 256.
//
// Two kernels:
//  1) wn_compute_h: 256 blocks (b,tile) compute the final hidden h once into d_ws
//     (row stride padded to 15364 so every tile start is 16B-aligned).
//  2) wn_stream:   2048 blocks (b,tile,channel-group of 32) read the 4KB h tile
//     (L2/L3-resident) and stream aligned float4 stores. Write volume == out size.

#define NL     10
#define B_     16
#define T_     16384
#define SHRINK 1023          // sum_{i<10} 2^i
#define LFIN   15361         // T_ - SHRINK
#define LPAD   15364         // LFIN rounded up to mult of 4 (alignment of h rows)
#define NC     256
#define TO     1024          // h outputs per tile
#define TILES  16            // ceil(LFIN / TO); last tile has 1 output
#define CG     8             // channel-groups per (b,tile)
#define CPW    32            // channels per group  (CG*CPW == NC)
#define NIN_MAX 2047         // TO + SHRINK

// ---------------- kernel 1: compute final hidden h[B][LPAD] into workspace ----------------
__global__ __launch_bounds__(256) void wn_compute_h(
    const float* __restrict__ x,      // [B][T]
    const float* __restrict__ cw,     // [NL][2]
    const float* __restrict__ cb,     // [NL]
    float* __restrict__ h)            // [B][LPAD]
{
    __shared__ float lds[2048];
    const int blk  = blockIdx.x;
    const int b    = blk >> 4;        // / TILES
    const int tile = blk & 15;
    const int s0   = tile * TO;
    int n_in = T_ - s0; if (n_in > NIN_MAX) n_in = NIN_MAX;
    const int tid = threadIdx.x;

    #pragma unroll
    for (int j = 0; j < 8; ++j) {
        int idx = tid + j * 256;
        if (idx < n_in) lds[idx] = x[b * T_ + s0 + idx];
    }
    __syncthreads();

    int cur = n_in;
    #pragma unroll
    for (int i = 0; i < NL; ++i) {
        const int d   = 1 << i;
        const int len = cur - d;
        const float w0 = cw[2 * i], w1 = cw[2 * i + 1], bbv = cb[i];
        float vals[8];
        #pragma unroll
        for (int j = 0; j < 8; ++j) {
            int t = tid + j * 256;
            if (t < len) {
                float v = fmaf(w0, lds[t], fmaf(w1, lds[t + d], bbv));
                vals[j] = v > 0.f ? v : 0.f;
            }
        }
        __syncthreads();
        #pragma unroll
        for (int j = 0; j < 8; ++j) {
            int t = tid + j * 256;
            if (t < len) lds[t] = vals[j];
        }
        __syncthreads();
        cur = len;
    }

    int n_out = LFIN - s0; if (n_out > TO) n_out = TO;
    #pragma unroll
    for (int j = 0; j < 4; ++j) {
        int t = tid + j * 256;
        if (t < n_out) h[b * LPAD + s0 + t] = lds[t];
    }
}

// ---------------- kernel 2: stream out[b][c][t] = ow[c]*h[b][t] + ob[c] ----------------
__global__ __launch_bounds__(256) void wn_stream(
    const float* __restrict__ h,      // [B][LPAD]
    const float* __restrict__ ow,     // [NC]
    const float* __restrict__ ob,     // [NC]
    float* __restrict__ out)          // [B][NC][LFIN]
{
    __shared__ float lds[1032];
    const int bid  = blockIdx.x;
    const int cg   = bid & (CG - 1);
    const int tile = (bid >> 3) & (TILES - 1);
    const int b    = bid >> 7;
    const int s0   = tile * TO;
    const int tid  = threadIdx.x;

    int n_out = LFIN - s0; if (n_out > TO) n_out = TO;

    // stage h tile: one aligned float4 per thread (reads past LFIN land in the
    // padded / oversized ws region -> safe, values unused)
    {
        float4 v = *reinterpret_cast<const float4*>(&h[(size_t)b * LPAD + s0 + 4 * tid]);
        *reinterpret_cast<float4*>(&lds[4 * tid]) = v;
    }
    __syncthreads();

    // hoist this thread's 8 h values (covers all 4 alignment windows)
    float4 hva = *reinterpret_cast<const float4*>(&lds[4 * tid]);
    float4 hvb = (tid < 255) ? *reinterpret_cast<const float4*>(&lds[4 * tid + 4])
                             : make_float4(0.f, 0.f, 0.f, 0.f);
    float hv[8] = {hva.x, hva.y, hva.z, hva.w, hvb.x, hvb.y, hvb.z, hvb.w};

    // row = b*NC + c0 + cc; start elem = row*LFIN + s0; LFIN%4==1, s0%4==0
    //   -> start%4 == cc%4 -> head length al0 = (4 - cc%4) & 3 (compile-time).
    const int c0 = cg * CPW;
    const size_t row0 = (size_t)(b * NC + c0);

    if (n_out == TO) {
        #pragma unroll
        for (int cc = 0; cc < CPW; ++cc) {
            const int al0 = (4 - (cc & 3)) & 3;       // compile-time
            const int nv  = (TO - al0) >> 2;          // 256 or 255
            const int rem = (TO - al0) & 3;           // 0..3
            const int tst = TO - rem;
            const int c = c0 + cc;
            const float w = ow[c], bs = ob[c];        // uniform -> scalar
            const size_t base = (row0 + cc) * LFIN + s0;

            if (al0 && tid < al0) out[base + tid] = fmaf(w, lds[tid], bs);
            if (tid < nv) {
                float4 v = make_float4(fmaf(w, hv[al0 + 0], bs),
                                       fmaf(w, hv[al0 + 1], bs),
                                       fmaf(w, hv[al0 + 2], bs),
                                       fmaf(w, hv[al0 + 3], bs));
                *reinterpret_cast<float4*>(&out[base + al0 + 4 * tid]) = v;
            }
            if (rem && tid < rem) out[base + tst + tid] = fmaf(w, lds[tst + tid], bs);
        }
    } else {
        // last tile (n_out == 1)
        #pragma unroll
        for (int cc = 0; cc < CPW; ++cc) {
            const int c = c0 + cc;
            const float w = ow[c], bs = ob[c];
            const size_t base = (row0 + cc) * LFIN + s0;
            if (tid < n_out) out[base + tid] = fmaf(w, lds[tid], bs);
        }
    }
}

// ---------------- fallback: round-2 fused kernel (if ws too small) ----------------
__global__ __launch_bounds__(256) void wn_fused_v2(
    const float* __restrict__ x, const float* __restrict__ cw, const float* __restrict__ cb,
    const float* __restrict__ ow, const float* __restrict__ ob, float* __restrict__ out)
{
    __shared__ float lds[2048];
    const int bid  = blockIdx.x;
    const int cg   = bid & (CG - 1);
    const int tile = (bid >> 3) & (TILES - 1);
    const int b    = bid >> 7;
    const int s0   = tile * TO;
    const int tid  = threadIdx.x;

    int n_in = T_ - s0; if (n_in > NIN_MAX) n_in = NIN_MAX;
    #pragma unroll
    for (int j = 0; j < 8; ++j) {
        int idx = tid + j * 256;
        if (idx < n_in) lds[idx] = x[b * T_ + s0 + idx];
    }
    __syncthreads();

    int cur = n_in;
    #pragma unroll
    for (int i = 0; i < NL; ++i) {
        const int d = 1 << i;
        const int len = cur - d;
        const float w0 = cw[2 * i], w1 = cw[2 * i + 1], bbv = cb[i];
        float vals[8];
        #pragma unroll
        for (int j = 0; j < 8; ++j) {
            int t = tid + j * 256;
            if (t < len) {
                float v = fmaf(w0, lds[t], fmaf(w1, lds[t + d], bbv));
                vals[j] = v > 0.f ? v : 0.f;
            }
        }
        __syncthreads();
        #pragma unroll
        for (int j = 0; j < 8; ++j) {
            int t = tid + j * 256;
            if (t < len) lds[t] = vals[j];
        }
        __syncthreads();
        cur = len;
    }

    int n_out = LFIN - s0; if (n_out > TO) n_out = TO;
    float4 hva = *reinterpret_cast<const float4*>(&lds[4 * tid]);
    float4 hvb = *reinterpret_cast<const float4*>(&lds[4 * tid + 4]);
    float hv[8] = {hva.x, hva.y, hva.z, hva.w, hvb.x, hvb.y, hvb.z, hvb.w};

    const int c0 = cg * CPW;
    const size_t row0 = (size_t)(b * NC + c0);
    #pragma unroll
    for (int cc = 0; cc < CPW; ++cc) {
        const int al0 = (4 - (cc & 3)) & 3;
        int al = al0 > n_out ? n_out : al0;
        const int c = c0 + cc;
        const float w = ow[c], bs = ob[c];
        const size_t base = (row0 + cc) * LFIN + s0;
        if (tid < al) out[base + tid] = fmaf(w, lds[tid], bs);
        const int nv = (n_out - al) >> 2;
        if (tid < nv) {
            const int t = al0 + 4 * tid;
            float4 v = make_float4(fmaf(w, hv[al0 + 0], bs),
                                   fmaf(w, hv[al0 + 1], bs),
                                   fmaf(w, hv[al0 + 2], bs),
                                   fmaf(w, hv[al0 + 3], bs));
            *reinterpret_cast<float4*>(&out[base + t]) = v;
        }
        const int rem = (n_out - al) & 3;
        const int tstart = al + 4 * nv;
        if (tid < rem) out[base + tstart + tid] = fmaf(w, lds[tstart + tid], bs);
    }
}

extern "C" void kernel_launch(void* const* d_in, const int* in_sizes, int n_in,
                              void* d_out, int out_size, void* d_ws, size_t ws_size,
                              hipStream_t stream) {
    const float* x  = (const float*)d_in[0];
    const float* cw = (const float*)d_in[1];
    const float* cb = (const float*)d_in[2];
    const float* ow = (const float*)d_in[3];
    const float* ob = (const float*)d_in[4];
    float* out = (float*)d_out;
    (void)in_sizes; (void)n_in; (void)out_size;

    const size_t need = (size_t)B_ * LPAD * sizeof(float) + 64;   // ~983 KB
    if (ws_size >= need) {
        float* h = (float*)d_ws;
        wn_compute_h<<<B_ * TILES, 256, 0, stream>>>(x, cw, cb, h);
        wn_stream<<<B_ * TILES * CG, 256, 0, stream>>>(h, ow, ob, out);
    } else {
        wn_fused_v2<<<B_ * TILES * CG, 256, 0, stream>>>(x, cw, cb, ow, ob, out);
    }
}

// Round 4
// 264.264 us; speedup vs baseline: 1.0310x; 1.0310x over previous
//
#include <hip/hip_runtime.h>

// WaveNet-ish: 10 stacked causal dilated conv1d (1ch, k=2, dil=2^i), then 1x1 -> 256ch.
// B=16, T=16384, receptive shrink 1023, final length 15361, classes 256.
//
// Single fat kernel: 256 blocks (one per CU; (b, t-tile of 1024)), 1024 threads.
// Prologue (stage x + 10 layers in LDS) runs ONCE per tile, then 4 subgroups of
// 256 threads stream all 256 channels (64 each) as aligned float4 stores with
// compile-time head/middle/tail split (c%4 static within the unrolled group).

#define NL     10
#define B_     16
#define T_     16384
#define SHRINK 1023          // sum_{i<10} 2^i
#define LFIN   15361         // T_ - SHRINK
#define NC     256
#define TO     1024          // h outputs per tile
#define TILES  16            // LFIN = 15*1024 + 1
#define NIN_MAX 2047         // TO + SHRINK

__global__ __launch_bounds__(1024) void wn_fat(
    const float* __restrict__ x,      // [B][T]
    const float* __restrict__ cw,     // [NL][2]
    const float* __restrict__ cb,     // [NL]
    const float* __restrict__ ow,     // [NC]
    const float* __restrict__ ob,     // [NC]
    float* __restrict__ out)          // [B][NC][LFIN]
{
    __shared__ float lds[2048];
    const int bid  = blockIdx.x;      // 0..255
    const int b    = bid >> 4;
    const int tile = bid & 15;
    const int s0   = tile * TO;
    const int tid  = threadIdx.x;

    int n_in = T_ - s0; if (n_in > NIN_MAX) n_in = NIN_MAX;

    // ---- stage x tile (coalesced, 2 elems/thread) ----
    {
        int i0 = tid, i1 = tid + 1024;
        if (i0 < n_in) lds[i0] = x[b * T_ + s0 + i0];
        if (i1 < n_in) lds[i1] = x[b * T_ + s0 + i1];
    }
    __syncthreads();

    // ---- 10 dilated conv layers in LDS (2 elems/thread) ----
    int cur = n_in;
    #pragma unroll
    for (int i = 0; i < NL; ++i) {
        const int d   = 1 << i;
        const int len = cur - d;
        const float w0 = cw[2 * i], w1 = cw[2 * i + 1], bbv = cb[i];
        float v0 = 0.f, v1 = 0.f;
        const int t0 = tid, t1 = tid + 1024;
        const bool p0 = t0 < len, p1 = t1 < len;
        if (p0) v0 = fmaxf(fmaf(w0, lds[t0], fmaf(w1, lds[t0 + d], bbv)), 0.f);
        if (p1) v1 = fmaxf(fmaf(w0, lds[t1], fmaf(w1, lds[t1 + d], bbv)), 0.f);
        __syncthreads();
        if (p0) lds[t0] = v0;
        if (p1) lds[t1] = v1;
        __syncthreads();
        cur = len;
    }

    int n_out = LFIN - s0; if (n_out > TO) n_out = TO;   // 1024, or 1 for tile 15

    const int ts  = tid & 255;        // lane-in-subgroup
    const int sub = tid >> 8;         // 0..3 -> channels [64*sub, 64*sub+64)
    const int cbase = sub << 6;

    // this thread's 8 h values (window covers all 4 alignment cases)
    float hv[8];
    {
        float4 a = *reinterpret_cast<const float4*>(&lds[4 * ts]);
        float4 q = *reinterpret_cast<const float4*>(&lds[4 * ts + 4]);  // <=1027 < 2048
        hv[0] = a.x; hv[1] = a.y; hv[2] = a.z; hv[3] = a.w;
        hv[4] = q.x; hv[5] = q.y; hv[6] = q.z; hv[7] = q.w;
    }

    if (n_out == TO) {
        // base element index of row (b, cbase) at column s0.
        // row%4 == c%4 (LFIN%4==1, s0%4==0) -> head length al0(q) = (4-q)&3, q=c%4.
        size_t base = ((size_t)(b * NC + cbase)) * LFIN + s0;
        #pragma unroll 4
        for (int g = 0; g < 16; ++g) {
            const int c = cbase + 4 * g;
            const float4 w4 = *reinterpret_cast<const float4*>(&ow[c]);  // uniform
            const float4 b4 = *reinterpret_cast<const float4*>(&ob[c]);

            // ---- q = 0: al0=0, nv=256, rem=0 ----
            {
                const float w = w4.x, bs = b4.x;
                float4 v = make_float4(fmaf(w, hv[0], bs), fmaf(w, hv[1], bs),
                                       fmaf(w, hv[2], bs), fmaf(w, hv[3], bs));
                *reinterpret_cast<float4*>(&out[base + 4 * ts]) = v;
            }
            // ---- q = 1: al0=3, nv=255, rem=1 ----
            {
                const float w = w4.y, bs = b4.y;
                const size_t bq = base + LFIN;
                if (ts < 3)   out[bq + ts] = fmaf(w, lds[ts], bs);
                if (ts < 255) {
                    float4 v = make_float4(fmaf(w, hv[3], bs), fmaf(w, hv[4], bs),
                                           fmaf(w, hv[5], bs), fmaf(w, hv[6], bs));
                    *reinterpret_cast<float4*>(&out[bq + 3 + 4 * ts]) = v;
                }
                if (ts < 1)   out[bq + 1023 + ts] = fmaf(w, lds[1023 + ts], bs);
            }
            // ---- q = 2: al0=2, nv=255, rem=2 ----
            {
                const float w = w4.z, bs = b4.z;
                const size_t bq = base + 2 * (size_t)LFIN;
                if (ts < 2)   out[bq + ts] = fmaf(w, lds[ts], bs);
                if (ts < 255) {
                    float4 v = make_float4(fmaf(w, hv[2], bs), fmaf(w, hv[3], bs),
                                           fmaf(w, hv[4], bs), fmaf(w, hv[5], bs));
                    *reinterpret_cast<float4*>(&out[bq + 2 + 4 * ts]) = v;
                }
                if (ts < 2)   out[bq + 1022 + ts] = fmaf(w, lds[1022 + ts], bs);
            }
            // ---- q = 3: al0=1, nv=255, rem=3 ----
            {
                const float w = w4.w, bs = b4.w;
                const size_t bq = base + 3 * (size_t)LFIN;
                if (ts < 1)   out[bq + ts] = fmaf(w, lds[ts], bs);
                if (ts < 255) {
                    float4 v = make_float4(fmaf(w, hv[1], bs), fmaf(w, hv[2], bs),
                                           fmaf(w, hv[3], bs), fmaf(w, hv[4], bs));
                    *reinterpret_cast<float4*>(&out[bq + 1 + 4 * ts]) = v;
                }
                if (ts < 3)   out[bq + 1021 + ts] = fmaf(w, lds[1021 + ts], bs);
            }
            base += 4 * (size_t)LFIN;
        }
    } else {
        // last tile: n_out == 1
        #pragma unroll 1
        for (int k = 0; k < 64; ++k) {
            const int c = cbase + k;
            const float w = ow[c], bs = ob[c];
            const size_t base = ((size_t)(b * NC + c)) * LFIN + s0;
            if (ts < n_out) out[base + ts] = fmaf(w, lds[ts], bs);
        }
    }
}

extern "C" void kernel_launch(void* const* d_in, const int* in_sizes, int n_in,
                              void* d_out, int out_size, void* d_ws, size_t ws_size,
                              hipStream_t stream) {
    const float* x  = (const float*)d_in[0];
    const float* cw = (const float*)d_in[1];
    const float* cb = (const float*)d_in[2];
    const float* ow = (const float*)d_in[3];
    const float* ob = (const float*)d_in[4];
    float* out = (float*)d_out;
    (void)d_ws; (void)ws_size; (void)in_sizes; (void)n_in; (void)out_size;

    wn_fat<<<B_ * TILES, 1024, 0, stream>>>(x, cw, cb, ow, ob, out);
}